// Round 2
// baseline (261.288 us; speedup 1.0000x reference)
//
#include <hip/hip_runtime.h>

typedef __attribute__((ext_vector_type(8))) short bf16x8;
typedef __attribute__((ext_vector_type(4))) float floatx4;

#define T_TREES 20
#define N_NODES 32      // padded (31 real internal nodes)
#define F_DIM 128
#define M_TILE 64
#define SP_STRIDE 68    // 64 rows + 4 pad: (c16*68+q*4)%32 -> max 2-way on b128 writes (free)

__device__ __forceinline__ short f2bf(float f) {
    unsigned u = __float_as_uint(f);
    u += 0x7fffu + ((u >> 16) & 1u);   // RNE
    return (short)(u >> 16);
}

__device__ __forceinline__ float fast_sigmoid(float z) {
    // rcp is ~1ulp approx: plenty under the 1e-2 bf16-class threshold
    return __builtin_amdgcn_rcpf(1.f + __expf(-z));
}

// ---------------- prep: masked bf16 weights, padded bias, scaled leaf class-0 values
__global__ void nrf_prep(const float* __restrict__ sw, const float* __restrict__ sb,
                         const float* __restrict__ ll, const float* __restrict__ tw,
                         const float* __restrict__ fm,
                         short* __restrict__ w_all, float* __restrict__ bias_p,
                         float* __restrict__ lv0) {
    int t = blockIdx.x, tid = threadIdx.x;
    float m = -1e30f;
    for (int i = 0; i < T_TREES; ++i) m = fmaxf(m, tw[i]);
    float s = 0.f;
    for (int i = 0; i < T_TREES; ++i) s += __expf(tw[i] - m);
    float wt = __expf(tw[t] - m) / s;

    const float* fmt = fm + t * F_DIM;
    const float* swt = sw + t * 31 * F_DIM;
    for (int idx = tid; idx < N_NODES * F_DIM; idx += blockDim.x) {
        int n = idx >> 7, f = idx & 127;
        float v = (n < 31) ? swt[n * F_DIM + f] * fmt[f] : 0.f;
        w_all[t * (N_NODES * F_DIM) + idx] = f2bf(v);
    }
    if (tid < N_NODES) {
        bias_p[t * N_NODES + tid] = (tid < 31) ? sb[t * 31 + tid] : 0.f;
        float a = ll[(t * 32 + tid) * 2 + 0], bb = ll[(t * 32 + tid) * 2 + 1];
        float mx = fmaxf(a, bb);
        float e0 = __expf(a - mx), e1 = __expf(bb - mx);
        lv0[t * N_NODES + tid] = wt * e0 / (e0 + e1);
    }
}

// ---------------- main: per-block 64 samples, fused GEMM+sigmoid+leaf-probs+reduce
__global__ __launch_bounds__(256, 6) void nrf_main(const float* __restrict__ x,
        const short* __restrict__ w_all, const float* __restrict__ bias_p,
        const float* __restrict__ lv0, float* __restrict__ out) {
    __shared__ float sp[2][N_NODES * SP_STRIDE];   // double-buffered: sp[node][row]
    __shared__ float lv_s[T_TREES * N_NODES];
    __shared__ float bias_s[T_TREES * N_NODES];
    __shared__ float red[256];

    int tid = threadIdx.x;
    int wave = tid >> 6, lane = tid & 63;
    int q = lane >> 4, c16 = lane & 15;

    for (int i = tid; i < T_TREES * N_NODES; i += 256) { lv_s[i] = lv0[i]; bias_s[i] = bias_p[i]; }

    // A fragments: x reused by all 20 trees -> load once into registers.
    // A-layout: m = lane&15, k = quad*8 + j  => 8 contiguous fp32.
    int m0 = wave * 16;
    int rowBase = blockIdx.x * M_TILE;
    bf16x8 afrag[4];
    {
        const float* xr = x + (size_t)(rowBase + m0 + c16) * F_DIM;
        #pragma unroll
        for (int ks = 0; ks < 4; ++ks) {
            const float4* p = (const float4*)(xr + ks * 32 + q * 8);
            float4 f0 = p[0], f1 = p[1];
            bf16x8 v;
            v[0]=f2bf(f0.x); v[1]=f2bf(f0.y); v[2]=f2bf(f0.z); v[3]=f2bf(f0.w);
            v[4]=f2bf(f1.x); v[5]=f2bf(f1.y); v[6]=f2bf(f1.z); v[7]=f2bf(f1.w);
            afrag[ks] = v;
        }
    }

    int b = tid & 63, h = tid >> 6;    // h = wave id = quarter-subtree (wave-uniform)
    int s_node = 3 + h;                // subtree root (level-2 node)
    float acc0 = 0.f;                  // class-0 accumulator over trees
    __syncthreads();                   // lv_s / bias_s ready

    for (int t = 0; t < T_TREES; ++t) {
        // B fragments from global (L2-resident): B-layout n=lane&15, k=quad*8+j
        bf16x8 bfrag[2][4];
        const short* wt = w_all + t * (N_NODES * F_DIM);
        #pragma unroll
        for (int ni = 0; ni < 2; ++ni) {
            const short* wr = wt + (ni * 16 + c16) * F_DIM;
            #pragma unroll
            for (int ks = 0; ks < 4; ++ks)
                bfrag[ni][ks] = *(const bf16x8*)(wr + ks * 32 + q * 8);
        }
        floatx4 acc[2];
        acc[0] = (floatx4){0.f,0.f,0.f,0.f};
        acc[1] = (floatx4){0.f,0.f,0.f,0.f};
        #pragma unroll
        for (int ks = 0; ks < 4; ++ks)
            #pragma unroll
            for (int ni = 0; ni < 2; ++ni)
                acc[ni] = __builtin_amdgcn_mfma_f32_16x16x32_bf16(
                    afrag[ks], bfrag[ni][ks], acc[ni], 0, 0, 0);

        // epilogue: bias + fast sigmoid, store transposed into buffer t&1
        float* spb = sp[t & 1];
        #pragma unroll
        for (int ni = 0; ni < 2; ++ni) {
            int col = ni * 16 + c16;
            float bv = bias_s[t * N_NODES + col];
            float4 v;
            v.x = fast_sigmoid(acc[ni][0] + bv);
            v.y = fast_sigmoid(acc[ni][1] + bv);
            v.z = fast_sigmoid(acc[ni][2] + bv);
            v.w = fast_sigmoid(acc[ni][3] + bv);
            *(float4*)&spb[col * SP_STRIDE + m0 + q * 4] = v;
        }
        __syncthreads();   // sp[t&1] visible; prior reads of this buffer were 2 barriers ago

        // leaf phase: thread = (sample b, quarter-subtree h). 9 LDS reads, ~28 VALU.
        float g0 = spb[b];                                  // root
        float g1 = spb[(1 + (h >> 1)) * SP_STRIDE + b];     // level-1 node on path
        float f0 = (h & 2) ? g0 : 1.f - g0;
        float f1 = (h & 1) ? g1 : 1.f - g1;
        float prefix = f0 * f1;

        float g2  = spb[s_node * SP_STRIDE + b];
        float g3a = spb[(2 * s_node + 1) * SP_STRIDE + b];
        float g3b = spb[(2 * s_node + 2) * SP_STRIDE + b];
        float g4a = spb[(4 * s_node + 3) * SP_STRIDE + b];
        float g4b = spb[(4 * s_node + 4) * SP_STRIDE + b];
        float g4c = spb[(4 * s_node + 5) * SP_STRIDE + b];
        float g4d = spb[(4 * s_node + 6) * SP_STRIDE + b];

        float p1 = prefix * g2, p0 = prefix - p1;
        float q1 = p0 * g3a, q0 = p0 - q1;
        float q3 = p1 * g3b, q2 = p1 - q3;
        float r1 = q0 * g4a, r0 = q0 - r1;
        float r3 = q1 * g4b, r2 = q1 - r3;
        float r5 = q2 * g4c, r4 = q2 - r5;
        float r7 = q3 * g4d, r6 = q3 - r7;

        const float* lvt = &lv_s[t * N_NODES + h * 8];      // wave-uniform -> LDS broadcast
        acc0 += r0*lvt[0] + r1*lvt[1] + r2*lvt[2] + r3*lvt[3]
              + r4*lvt[4] + r5*lvt[5] + r6*lvt[6] + r7*lvt[7];
    }

    // combine 4 quarter partials per sample; out1 = 1 - out0 (prob masses sum to 1)
    red[tid] = acc0;
    __syncthreads();
    if (tid < M_TILE) {
        float tot = red[tid] + red[tid + 64] + red[tid + 128] + red[tid + 192];
        float2 o; o.x = tot; o.y = 1.f - tot;
        *(float2*)(out + (size_t)(rowBase + tid) * 2) = o;
    }
}

extern "C" void kernel_launch(void* const* d_in, const int* in_sizes, int n_in,
                              void* d_out, int out_size, void* d_ws, size_t ws_size,
                              hipStream_t stream) {
    const float* x  = (const float*)d_in[0];
    const float* sw = (const float*)d_in[1];
    const float* sb = (const float*)d_in[2];
    const float* ll = (const float*)d_in[3];
    const float* tw = (const float*)d_in[4];
    const float* fm = (const float*)d_in[5];
    float* out = (float*)d_out;

    short* w_all  = (short*)d_ws;                         // 20*32*128*2 = 163840 B
    float* bias_p = (float*)((char*)d_ws + 163840);       // 2560 B
    float* lv0    = (float*)((char*)d_ws + 166400);       // 2560 B

    nrf_prep<<<T_TREES, 256, 0, stream>>>(sw, sb, ll, tw, fm, w_all, bias_p, lv0);

    int B = in_sizes[0] / F_DIM;                          // 131072
    nrf_main<<<B / M_TILE, 256, 0, stream>>>(x, w_all, bias_p, lv0, out);
}

// Round 3
// 179.311 us; speedup vs baseline: 1.4572x; 1.4572x over previous
//
#include <hip/hip_runtime.h>

typedef __attribute__((ext_vector_type(8))) short bf16x8;
typedef __attribute__((ext_vector_type(4))) float floatx4;

#define T_TREES 20
#define N_NODES 32      // padded (31 real internal nodes)
#define F_DIM 128
#define M_TILE 128      // 4 waves x 32 rows, wave-private leaf phase
#define S_SP 36         // sp stride (dwords): 32 rows + 4 pad (reads <=2-way conflict)

#define NLOG2E 1.4426950408889634f   // weights pre-scaled by -log2(e)

__device__ __forceinline__ short f2bf(float f) {
    unsigned u = __float_as_uint(f);
    u += 0x7fffu + ((u >> 16) & 1u);   // RNE
    return (short)(u >> 16);
}

// sigma(z) with acc = -z*log2(e) already: 1/(1+2^acc). 2 VALU + 2 trans ops.
__device__ __forceinline__ float sig_from_scaled(float u) {
    return __builtin_amdgcn_rcpf(1.f + __builtin_amdgcn_exp2f(u));
}

// ---------------- prep: masked bf16 weights (x -log2e), scaled bias, leaf class-0 values
__global__ void nrf_prep(const float* __restrict__ sw, const float* __restrict__ sb,
                         const float* __restrict__ ll, const float* __restrict__ tw,
                         const float* __restrict__ fm,
                         short* __restrict__ w_all, float* __restrict__ bias_p,
                         float* __restrict__ lv0) {
    int t = blockIdx.x, tid = threadIdx.x;
    float m = -1e30f;
    for (int i = 0; i < T_TREES; ++i) m = fmaxf(m, tw[i]);
    float s = 0.f;
    for (int i = 0; i < T_TREES; ++i) s += __expf(tw[i] - m);
    float wt = __expf(tw[t] - m) / s;

    const float* fmt = fm + t * F_DIM;
    const float* swt = sw + t * 31 * F_DIM;
    for (int idx = tid; idx < N_NODES * F_DIM; idx += blockDim.x) {
        int n = idx >> 7, f = idx & 127;
        float v = (n < 31) ? swt[n * F_DIM + f] * fmt[f] * (-NLOG2E) : 0.f;
        w_all[t * (N_NODES * F_DIM) + idx] = f2bf(v);
    }
    if (tid < N_NODES) {
        bias_p[t * N_NODES + tid] = (tid < 31) ? sb[t * 31 + tid] * (-NLOG2E) : 0.f;
        float a = ll[(t * 32 + tid) * 2 + 0], bb = ll[(t * 32 + tid) * 2 + 1];
        float mx = fmaxf(a, bb);
        float e0 = __expf(a - mx), e1 = __expf(bb - mx);
        lv0[t * N_NODES + tid] = wt * e0 / (e0 + e1);
    }
}

// ---------------- main: zero barriers in the tree loop; sp is wave-private LDS
__global__ __launch_bounds__(256) void nrf_main(const float* __restrict__ x,
        const short* __restrict__ w_all, const float* __restrict__ bias_p,
        const float* __restrict__ lv0, float* __restrict__ out) {
    __shared__ float sp_all[4][N_NODES * S_SP];   // one patch per wave
    __shared__ float lv_s[T_TREES * N_NODES];
    __shared__ float bias_s[T_TREES * N_NODES];

    int tid = threadIdx.x;
    int wave = tid >> 6, lane = tid & 63;
    int q = lane >> 4, c16 = lane & 15;

    for (int i = tid; i < T_TREES * N_NODES; i += 256) { lv_s[i] = lv0[i]; bias_s[i] = bias_p[i]; }

    float* spb = sp_all[wave];
    int rowBase = blockIdx.x * M_TILE + wave * 32;   // this wave's 32 rows

    // A fragments: x reused by all 20 trees -> registers. A-layout m=lane&15, k=q*8+j.
    bf16x8 afrag[2][4];
    #pragma unroll
    for (int mi = 0; mi < 2; ++mi) {
        const float* xr = x + (size_t)(rowBase + mi * 16 + c16) * F_DIM;
        #pragma unroll
        for (int ks = 0; ks < 4; ++ks) {
            const float4* p = (const float4*)(xr + ks * 32 + q * 8);
            float4 f0 = p[0], f1 = p[1];
            bf16x8 v;
            v[0]=f2bf(f0.x); v[1]=f2bf(f0.y); v[2]=f2bf(f0.z); v[3]=f2bf(f0.w);
            v[4]=f2bf(f1.x); v[5]=f2bf(f1.y); v[6]=f2bf(f1.z); v[7]=f2bf(f1.w);
            afrag[mi][ks] = v;
        }
    }

    int s = lane & 15, h = lane >> 4;   // leaf job: rows s & s+16, quarter-subtree h
    int s_node = 3 + h;                 // quarter root (level-2 node)
    float acc0 = 0.f, acc1 = 0.f;
    __syncthreads();                    // ONLY barrier: lv_s/bias_s ready

    for (int t = 0; t < T_TREES; ++t) {
        // B fragments from global (L2-resident). No barrier ahead -> compiler can
        // hoist these over the previous tree's leaf phase (software pipelining).
        bf16x8 bfrag[2][4];
        const short* wt = w_all + t * (N_NODES * F_DIM);
        #pragma unroll
        for (int ni = 0; ni < 2; ++ni) {
            const short* wr = wt + (ni * 16 + c16) * F_DIM;
            #pragma unroll
            for (int ks = 0; ks < 4; ++ks)
                bfrag[ni][ks] = *(const bf16x8*)(wr + ks * 32 + q * 8);
        }
        floatx4 acc[2][2];
        #pragma unroll
        for (int mi = 0; mi < 2; ++mi)
            #pragma unroll
            for (int ni = 0; ni < 2; ++ni)
                acc[mi][ni] = (floatx4){0.f,0.f,0.f,0.f};
        #pragma unroll
        for (int ks = 0; ks < 4; ++ks)
            #pragma unroll
            for (int mi = 0; mi < 2; ++mi)
                #pragma unroll
                for (int ni = 0; ni < 2; ++ni)
                    acc[mi][ni] = __builtin_amdgcn_mfma_f32_16x16x32_bf16(
                        afrag[mi][ks], bfrag[ni][ks], acc[mi][ni], 0, 0, 0);

        // epilogue: sigma = rcp(1+exp2(acc+bias)); transposed wave-private store
        #pragma unroll
        for (int ni = 0; ni < 2; ++ni) {
            int col = ni * 16 + c16;
            float bv = bias_s[t * N_NODES + col];
            #pragma unroll
            for (int mi = 0; mi < 2; ++mi) {
                float4 v;
                v.x = sig_from_scaled(acc[mi][ni][0] + bv);
                v.y = sig_from_scaled(acc[mi][ni][1] + bv);
                v.z = sig_from_scaled(acc[mi][ni][2] + bv);
                v.w = sig_from_scaled(acc[mi][ni][3] + bv);
                *(float4*)&spb[col * S_SP + mi * 16 + q * 4] = v;
            }
        }
        // leaf phase: wave-private LDS, DS ops in-order per wave -> NO barrier.
        // read 9 nodes x 2 rows (pairs s, s+16 -> ds_read2 friendly)
        float g0a = spb[s],                          g0b = spb[s + 16];
        int n1 = 1 + (h >> 1);
        float g1a = spb[n1 * S_SP + s],              g1b = spb[n1 * S_SP + s + 16];
        float g2a = spb[s_node * S_SP + s],          g2b = spb[s_node * S_SP + s + 16];
        int n3a = 2 * s_node + 1, n3b = 2 * s_node + 2;
        float g3aa = spb[n3a * S_SP + s],            g3ab = spb[n3a * S_SP + s + 16];
        float g3ba = spb[n3b * S_SP + s],            g3bb = spb[n3b * S_SP + s + 16];
        int n4 = 4 * s_node + 3;
        float g4aa = spb[n4 * S_SP + s],             g4ab = spb[n4 * S_SP + s + 16];
        float g4ba = spb[(n4+1) * S_SP + s],         g4bb = spb[(n4+1) * S_SP + s + 16];
        float g4ca = spb[(n4+2) * S_SP + s],         g4cb = spb[(n4+2) * S_SP + s + 16];
        float g4da = spb[(n4+3) * S_SP + s],         g4db = spb[(n4+3) * S_SP + s + 16];

        const float* lvt = &lv_s[t * N_NODES + h * 8];  // shared by both rows

        {   // row s
            float f0 = (h & 2) ? g0a : 1.f - g0a;
            float f1 = (h & 1) ? g1a : 1.f - g1a;
            float pre = f0 * f1;
            float p1 = pre * g2a, p0 = pre - p1;
            float q1 = p0 * g3aa, q0 = p0 - q1;
            float q3 = p1 * g3ba, q2 = p1 - q3;
            float r1 = q0 * g4aa, r0 = q0 - r1;
            float r3 = q1 * g4ba, r2 = q1 - r3;
            float r5 = q2 * g4ca, r4 = q2 - r5;
            float r7 = q3 * g4da, r6 = q3 - r7;
            acc0 += r0*lvt[0] + r1*lvt[1] + r2*lvt[2] + r3*lvt[3]
                  + r4*lvt[4] + r5*lvt[5] + r6*lvt[6] + r7*lvt[7];
        }
        {   // row s+16
            float f0 = (h & 2) ? g0b : 1.f - g0b;
            float f1 = (h & 1) ? g1b : 1.f - g1b;
            float pre = f0 * f1;
            float p1 = pre * g2b, p0 = pre - p1;
            float q1 = p0 * g3ab, q0 = p0 - q1;
            float q3 = p1 * g3bb, q2 = p1 - q3;
            float r1 = q0 * g4ab, r0 = q0 - r1;
            float r3 = q1 * g4bb, r2 = q1 - r3;
            float r5 = q2 * g4cb, r4 = q2 - r5;
            float r7 = q3 * g4db, r6 = q3 - r7;
            acc1 += r0*lvt[0] + r1*lvt[1] + r2*lvt[2] + r3*lvt[3]
                  + r4*lvt[4] + r5*lvt[5] + r6*lvt[6] + r7*lvt[7];
        }
    }

    // cross-quarter reduce inside the wave; out1 = 1 - out0 (prob mass sums to 1)
    acc0 += __shfl_xor(acc0, 16, 64);
    acc0 += __shfl_xor(acc0, 32, 64);
    acc1 += __shfl_xor(acc1, 16, 64);
    acc1 += __shfl_xor(acc1, 32, 64);
    if (h == 0) {
        float2 o0; o0.x = acc0; o0.y = 1.f - acc0;
        *(float2*)(out + (size_t)(rowBase + s) * 2) = o0;
        float2 o1; o1.x = acc1; o1.y = 1.f - acc1;
        *(float2*)(out + (size_t)(rowBase + 16 + s) * 2) = o1;
    }
}

extern "C" void kernel_launch(void* const* d_in, const int* in_sizes, int n_in,
                              void* d_out, int out_size, void* d_ws, size_t ws_size,
                              hipStream_t stream) {
    const float* x  = (const float*)d_in[0];
    const float* sw = (const float*)d_in[1];
    const float* sb = (const float*)d_in[2];
    const float* ll = (const float*)d_in[3];
    const float* tw = (const float*)d_in[4];
    const float* fm = (const float*)d_in[5];
    float* out = (float*)d_out;

    short* w_all  = (short*)d_ws;                         // 20*32*128*2 = 163840 B
    float* bias_p = (float*)((char*)d_ws + 163840);       // 2560 B
    float* lv0    = (float*)((char*)d_ws + 166400);       // 2560 B

    nrf_prep<<<T_TREES, 256, 0, stream>>>(sw, sb, ll, tw, fm, w_all, bias_p, lv0);

    int B = in_sizes[0] / F_DIM;                          // 131072
    nrf_main<<<B / M_TILE, 256, 0, stream>>>(x, w_all, bias_p, lv0, out);
}